// Round 4
// baseline (743.358 us; speedup 1.0000x reference)
//
#include <hip/hip_runtime.h>
#include <hip/hip_bf16.h>

// ---------------------------------------------------------------------------
// IterativeVoxelModel: 3-layer windowed attention. N = 256*27 = 6912 tokens,
// d=256, heads=8 (hd=32), ffn=1024.
// R3 (resubmit after infra timeout): attention is block-diagonal per patch
// (27 tokens) -> patch-resident LDS attention kernel. Q/K/V fused dispatch.
// ---------------------------------------------------------------------------

#define NTOK 6912
#define DM   256
#define FF   1024

typedef __hip_bfloat16 bf16;
typedef __bf16 bf16x8 __attribute__((ext_vector_type(8)));
typedef float  f32x4  __attribute__((ext_vector_type(4)));

__device__ __forceinline__ void gload_lds16(const void* g, void* l) {
    __builtin_amdgcn_global_load_lds(
        (const __attribute__((address_space(1))) void*)g,
        (__attribute__((address_space(3))) void*)l, 16, 0, 0);
}

// ---------------- embed: t = np * w_in + b_in + pos_embed ------------------
__global__ __launch_bounds__(256) void embed_kernel(
    const float* __restrict__ npat, const float* __restrict__ w_in,
    const float* __restrict__ b_in, const float* __restrict__ pos,
    float* __restrict__ t, bf16* __restrict__ t_bf)
{
    int n = blockIdx.x;
    int c = threadIdx.x;
    int p = n % 27;
    float v = npat[n] * w_in[c] + b_in[c] + pos[p * DM + c];
    t[(size_t)n * DM + c] = v;
    t_bf[(size_t)n * DM + c] = __float2bfloat16(v);
}

// ---------------- mask: 27-bit neighborhood mask per token -----------------
__global__ void make_mask_kernel(const int* __restrict__ km,
                                 unsigned int* __restrict__ maskbits)
{
    int n = blockIdx.x * blockDim.x + threadIdx.x;
    if (n >= NTOK) return;
    int b = n / 27, p = n % 27;
    int zc = p / 9, yc = (p / 3) % 3, xc = p % 3;
    unsigned int mb = 0u;
    for (int j = 0; j < 27; ++j) {
        int z = zc + j / 9 - 1;
        int y = yc + (j / 3) % 3 - 1;
        int x = xc + j % 3 - 1;
        if (z >= 0 && z < 3 && y >= 0 && y < 3 && x >= 0 && x < 3 &&
            km[b * 27 + z * 9 + y * 3 + x] != 0)
            mb |= (1u << j);
    }
    maskbits[n] = mb;
}

// ---------------- weight convert+transpose: W[K][N] f32 -> Wt[N][K] bf16 ---
__global__ __launch_bounds__(256) void convert_weights(
    const float* __restrict__ Wq, const float* __restrict__ Wk,
    const float* __restrict__ Wv, const float* __restrict__ Wo,
    const float* __restrict__ W1, const float* __restrict__ W2,
    bf16* __restrict__ Wt)
{
    __shared__ float tile[32][33];
    int id = blockIdx.z;
    int l = id / 6, wsel = id % 6;
    const float* src; bf16* dst; int K, N;
    if (wsel < 4) {
        const float* tbl[4] = {Wq, Wk, Wv, Wo};
        src = tbl[wsel] + (size_t)l * 65536; K = 256; N = 256;
        dst = Wt + (size_t)l * 786432 + wsel * 65536;
    } else if (wsel == 4) {
        src = W1 + (size_t)l * 262144; K = 256; N = 1024;
        dst = Wt + (size_t)l * 786432 + 262144;
    } else {
        src = W2 + (size_t)l * 262144; K = 1024; N = 256;
        dst = Wt + (size_t)l * 786432 + 524288;
    }
    int n0 = blockIdx.x * 32, k0 = blockIdx.y * 32;
    if (n0 >= N || k0 >= K) return;
    int tx = threadIdx.x, ty = threadIdx.y;   // 32 x 8
#pragma unroll
    for (int i = 0; i < 4; ++i)
        tile[ty + i * 8][tx] = src[(size_t)(k0 + ty + i * 8) * N + n0 + tx];
    __syncthreads();
#pragma unroll
    for (int i = 0; i < 4; ++i)
        dst[(size_t)(n0 + ty + i * 8) * K + k0 + tx] =
            __float2bfloat16(tile[tx][ty + i * 8]);
}

// ---------------- layernorm over d=256, one block per token ----------------
__global__ __launch_bounds__(256) void layernorm_kernel(
    const float* __restrict__ X, const float* __restrict__ g,
    const float* __restrict__ bta, bf16* __restrict__ Y)
{
    int n = blockIdx.x;
    int c = threadIdx.x;
    float x = X[(size_t)n * DM + c];
    float s = x, s2 = x * x;
    for (int off = 32; off; off >>= 1) {
        s  += __shfl_xor(s, off);
        s2 += __shfl_xor(s2, off);
    }
    __shared__ float ps[4], ps2[4];
    int w = c >> 6;
    if ((c & 63) == 0) { ps[w] = s; ps2[w] = s2; }
    __syncthreads();
    s  = ps[0] + ps[1] + ps[2] + ps[3];
    s2 = ps2[0] + ps2[1] + ps2[2] + ps2[3];
    float mu  = s * (1.0f / DM);
    float var = s2 * (1.0f / DM) - mu * mu;
    float r = rsqrtf(var + 1e-5f);
    Y[(size_t)n * DM + c] = __float2bfloat16((x - mu) * r * g[c] + bta[c]);
}

// ---------------- bf16 MFMA GEMM body (128x64 tile, 4 waves) ---------------
__device__ __forceinline__ void gemm_body(
    const bf16* __restrict__ A, const bf16* __restrict__ Bt,
    const float* __restrict__ bias, const float* __restrict__ residual,
    float* __restrict__ Cf, bf16* __restrict__ Cb,
    int K, int Nc, int act, int row0, int col0,
    bf16* As, bf16* Bs)
{
    int tid = threadIdx.x;
    int wv = tid >> 6, ln = tid & 63;
    int wr = wv >> 1, wc = wv & 1;

    f32x4 acc[4][2];
#pragma unroll
    for (int m = 0; m < 4; ++m)
#pragma unroll
        for (int n = 0; n < 2; ++n) acc[m][n] = (f32x4){0.f, 0.f, 0.f, 0.f};

    int lrow = ln >> 3;          // 0..7 row within 1KB chunk
    int kof  = (ln & 7) * 8;     // bf16 offset within 64-elem row

    for (int k0 = 0; k0 < K; k0 += 64) {
        __syncthreads();
#pragma unroll
        for (int i = 0; i < 4; ++i) {
            int slot = i * 4 + wv;                    // 0..15 (8 rows each)
            gload_lds16(A + (size_t)(row0 + slot * 8 + lrow) * K + k0 + kof,
                        As + slot * 512);
        }
#pragma unroll
        for (int i = 0; i < 2; ++i) {
            int slot = i * 4 + wv;                    // 0..7
            gload_lds16(Bt + (size_t)(col0 + slot * 8 + lrow) * K + k0 + kof,
                        Bs + slot * 512);
        }
        __syncthreads();
        int lr = ln & 15, kg = ln >> 4;
#pragma unroll
        for (int kk = 0; kk < 2; ++kk) {
            int koff = kk * 32 + kg * 8;
            bf16x8 a[4], b[2];
#pragma unroll
            for (int m = 0; m < 4; ++m)
                a[m] = *(const bf16x8*)&As[(wr * 64 + m * 16 + lr) * 64 + koff];
#pragma unroll
            for (int n = 0; n < 2; ++n)
                b[n] = *(const bf16x8*)&Bs[(wc * 32 + n * 16 + lr) * 64 + koff];
#pragma unroll
            for (int m = 0; m < 4; ++m)
#pragma unroll
                for (int n = 0; n < 2; ++n)
                    acc[m][n] = __builtin_amdgcn_mfma_f32_16x16x32_bf16(
                        a[m], b[n], acc[m][n], 0, 0, 0);
        }
    }

    int lr = ln & 15, rg = ln >> 4;
#pragma unroll
    for (int m = 0; m < 4; ++m) {
#pragma unroll
        for (int n = 0; n < 2; ++n) {
            int col = col0 + wc * 32 + n * 16 + lr;
            float bcol = bias[col];
#pragma unroll
            for (int r = 0; r < 4; ++r) {
                int row = row0 + wr * 64 + m * 16 + rg * 4 + r;
                size_t idx = (size_t)row * Nc + col;
                float v = acc[m][n][r] + bcol;
                if (residual) v += residual[idx];
                if (act) v = 0.5f * v * (1.0f + erff(v * 0.70710678118654752f));
                if (Cf) Cf[idx] = v;
                if (Cb) Cb[idx] = __float2bfloat16(v);
            }
        }
    }
}

__global__ __launch_bounds__(256) void gemm_bf16(
    const bf16* __restrict__ A, const bf16* __restrict__ Bt,
    const float* __restrict__ bias, const float* __restrict__ residual,
    float* __restrict__ Cf, bf16* __restrict__ Cb,
    int K, int Nc, int act)
{
    __shared__ __align__(16) bf16 As[128 * 64];
    __shared__ __align__(16) bf16 Bs[64 * 64];
    gemm_body(A, Bt, bias, residual, Cf, Cb, K, Nc, act,
              blockIdx.x * 128, blockIdx.y * 64, As, Bs);
}

// fused Q/K/V projection: grid (54, 12); y>>2 selects {Q,K,V}
__global__ __launch_bounds__(256) void qkv_gemm(
    const bf16* __restrict__ tn, const bf16* __restrict__ tb,
    const bf16* __restrict__ wq,              // wq,wk,wv contiguous (65536 apart)
    const float* __restrict__ bq, const float* __restrict__ bk,
    const float* __restrict__ bv,
    float* __restrict__ Qf, float* __restrict__ Kf, float* __restrict__ Vf)
{
    __shared__ __align__(16) bf16 As[128 * 64];
    __shared__ __align__(16) bf16 Bs[64 * 64];
    int ysel = blockIdx.y >> 2, ycol = blockIdx.y & 3;
    const bf16* A = (ysel == 0) ? tn : tb;
    const bf16* W = wq + (size_t)ysel * 65536;
    const float* bias = (ysel == 0) ? bq : (ysel == 1) ? bk : bv;
    float* Out = (ysel == 0) ? Qf : (ysel == 1) ? Kf : Vf;
    gemm_body(A, W, bias, nullptr, Out, nullptr, DM, DM, 0,
              blockIdx.x * 128, ycol * 64, As, Bs);
}

// ---------------- patch-resident attention: one block per patch ------------
__global__ __launch_bounds__(256) void attention_patch_kernel(
    const float* __restrict__ Q, const float* __restrict__ K,
    const float* __restrict__ V, const unsigned int* __restrict__ maskbits,
    bf16* __restrict__ out)
{
    __shared__ float Ks[27 * 256];
    __shared__ float Vs[27 * 256];
    int b = blockIdx.x;
    int tid = threadIdx.x;              // h*32 + d
    const float4* Kp = (const float4*)(K + (size_t)b * 27 * 256);
    const float4* Vp = (const float4*)(V + (size_t)b * 27 * 256);
#pragma unroll
    for (int i = 0; i < 7; ++i) {
        int idx = tid + i * 256;        // float4 slot, 27*64=1728 total
        if (idx < 1728) {
            ((float4*)Ks)[idx] = Kp[idx];
            ((float4*)Vs)[idx] = Vp[idx];
        }
    }
    __syncthreads();

    for (int tok = 0; tok < 27; ++tok) {
        int zc = tok / 9, yc = (tok / 3) % 3, xc = tok % 3;
        unsigned int mb = maskbits[b * 27 + tok];   // block-uniform
        float qv = Q[((size_t)b * 27 + tok) * DM + tid];

        float s[27];
        float mx = -1e30f;
#pragma unroll
        for (int j = 0; j < 27; ++j) {
            if (mb & (1u << j)) {
                int ml = (zc + j / 9 - 1) * 9 + (yc + (j / 3) % 3 - 1) * 3
                       + (xc + j % 3 - 1);
                float partial = qv * Ks[ml * 256 + tid];
                for (int off = 16; off; off >>= 1)
                    partial += __shfl_xor(partial, off, 32);
                s[j] = partial * 0.17677669529663687f;   // 1/sqrt(32)
                mx = fmaxf(mx, s[j]);
            }
        }
        float sum = 0.f;
#pragma unroll
        for (int j = 0; j < 27; ++j) {
            if (mb & (1u << j)) { s[j] = expf(s[j] - mx); sum += s[j]; }
        }
        float inv = (sum > 0.f) ? 1.f / sum : 0.f;
        float o = 0.f;
#pragma unroll
        for (int j = 0; j < 27; ++j) {
            if (mb & (1u << j)) {
                int ml = (zc + j / 9 - 1) * 9 + (yc + (j / 3) % 3 - 1) * 3
                       + (xc + j % 3 - 1);
                o = fmaf(s[j] * inv, Vs[ml * 256 + tid], o);
            }
        }
        out[((size_t)b * 27 + tok) * DM + tid] = __float2bfloat16(o);
    }
}

// ---------------- output: out[b] = t[center(b)] . w_out + b_out ------------
__global__ __launch_bounds__(256) void out_proj_kernel(
    const float* __restrict__ t, const float* __restrict__ w_out,
    const float* __restrict__ b_out, float* __restrict__ out)
{
    int bb = blockIdx.x;
    int c = threadIdx.x;
    float v = t[(size_t)(bb * 27 + 13) * DM + c] * w_out[c];
    for (int off = 32; off; off >>= 1) v += __shfl_xor(v, off);
    __shared__ float ps[4];
    if ((c & 63) == 0) ps[c >> 6] = v;
    __syncthreads();
    if (c == 0) out[bb] = ps[0] + ps[1] + ps[2] + ps[3] + b_out[0];
}

// ---------------------------------------------------------------------------
extern "C" void kernel_launch(void* const* d_in, const int* in_sizes, int n_in,
                              void* d_out, int out_size, void* d_ws, size_t ws_size,
                              hipStream_t stream)
{
    const float* npat  = (const float*)d_in[0];
    const int*   kmask = (const int*)  d_in[1];
    const float* w_in  = (const float*)d_in[2];
    const float* b_in  = (const float*)d_in[3];
    const float* pos   = (const float*)d_in[4];
    const float* ln1_g = (const float*)d_in[5];
    const float* ln1_b = (const float*)d_in[6];
    const float* ln2_g = (const float*)d_in[7];
    const float* ln2_b = (const float*)d_in[8];
    const float* Wq    = (const float*)d_in[9];
    const float* bq    = (const float*)d_in[10];
    const float* Wk    = (const float*)d_in[11];
    const float* bk    = (const float*)d_in[12];
    const float* Wv    = (const float*)d_in[13];
    const float* bv    = (const float*)d_in[14];
    const float* Wo    = (const float*)d_in[15];
    const float* bo    = (const float*)d_in[16];
    const float* W1    = (const float*)d_in[17];
    const float* b1    = (const float*)d_in[18];
    const float* W2    = (const float*)d_in[19];
    const float* b2    = (const float*)d_in[20];
    const float* w_out = (const float*)d_in[21];
    const float* b_out = (const float*)d_in[22];
    float* out = (float*)d_out;

    // workspace carve-up
    char* ws = (char*)d_ws;
    size_t f32mat = (size_t)NTOK * DM * 4;   // 7,077,888
    size_t bfmat  = (size_t)NTOK * DM * 2;   // 3,538,944
    float* t    = (float*)(ws);
    float* Qf   = (float*)(ws + f32mat);
    float* Kf   = (float*)(ws + 2 * f32mat);
    float* Vf   = (float*)(ws + 3 * f32mat);
    char* p = ws + 4 * f32mat;
    bf16* t_bf   = (bf16*)(p);               p += bfmat;
    bf16* tn_bf  = (bf16*)(p);               p += bfmat;
    bf16* attn_bf= (bf16*)(p);               p += bfmat;
    bf16* H_bf   = (bf16*)(p);               p += (size_t)NTOK * FF * 2;
    bf16* Wt     = (bf16*)(p);               p += (size_t)3 * 786432 * 2;
    unsigned int* maskbits = (unsigned int*)(p);

    convert_weights<<<dim3(32, 32, 18), dim3(32, 8), 0, stream>>>(
        Wq, Wk, Wv, Wo, W1, W2, Wt);
    embed_kernel<<<NTOK, 256, 0, stream>>>(npat, w_in, b_in, pos, t, t_bf);
    make_mask_kernel<<<(NTOK + 255) / 256, 256, 0, stream>>>(kmask, maskbits);

    dim3 gDD(NTOK / 128, DM / 64);    // (54, 4)
    dim3 gQKV(NTOK / 128, 12);        // (54, 12)
    dim3 gFF(NTOK / 128, FF / 64);    // (54, 16)

    for (int l = 0; l < 3; ++l) {
        const bf16* wqt = Wt + (size_t)l * 786432;
        const bf16* wot = wqt + 3 * 65536;
        const bf16* w1t = wot + 65536;
        const bf16* w2t = w1t + 262144;

        layernorm_kernel<<<NTOK, 256, 0, stream>>>(t, ln1_g + l * DM, ln1_b + l * DM, tn_bf);
        qkv_gemm<<<gQKV, 256, 0, stream>>>(tn_bf, t_bf, wqt,
                                           bq + l * DM, bk + l * DM, bv + l * DM,
                                           Qf, Kf, Vf);
        attention_patch_kernel<<<256, 256, 0, stream>>>(Qf, Kf, Vf, maskbits, attn_bf);
        gemm_bf16<<<gDD, 256, 0, stream>>>(attn_bf, wot, bo + l * DM, t, t, t_bf, DM, DM, 0);
        layernorm_kernel<<<NTOK, 256, 0, stream>>>(t, ln2_g + l * DM, ln2_b + l * DM, tn_bf);
        gemm_bf16<<<gFF, 256, 0, stream>>>(tn_bf, w1t, b1 + l * FF, nullptr, nullptr, H_bf, DM, FF, 1);
        gemm_bf16<<<gDD, 256, 0, stream>>>(H_bf, w2t, b2 + l * DM, t, t, t_bf, FF, DM, 0);
    }

    out_proj_kernel<<<256, 256, 0, stream>>>(t, w_out, b_out, out);
}

// Round 6
// 391.444 us; speedup vs baseline: 1.8990x; 1.8990x over previous
//
#include <hip/hip_runtime.h>
#include <hip/hip_bf16.h>

// ---------------------------------------------------------------------------
// IterativeVoxelModel: 3-layer windowed attention. N = 256*27 = 6912 tokens,
// d=256, heads=8 (hd=32), ffn=1024.
// R5 (resubmit after infra timeout): MFMA attention. Per patch, attention is
// S^T = K·Q^T (27x27, K=hd=32) and O = P·V -- 8 MFMAs per head. One wave per
// (patch, head), swapped operands make the neighbor axis lane-local for
// softmax (2 shfl_xor only). Masks are per-query 27-bit token-token words.
// V emitted pre-transposed (bf16) by the QKV GEMM epilogue.
// ---------------------------------------------------------------------------

#define NTOK 6912
#define DM   256
#define FF   1024

typedef __hip_bfloat16 bf16;
typedef __bf16 bf16x8 __attribute__((ext_vector_type(8)));
typedef float  f32x4  __attribute__((ext_vector_type(4)));

__device__ __forceinline__ void gload_lds16(const void* g, void* l) {
    __builtin_amdgcn_global_load_lds(
        (const __attribute__((address_space(1))) void*)g,
        (__attribute__((address_space(3))) void*)l, 16, 0, 0);
}

__device__ __forceinline__ unsigned short f2bf_bits(float x) {
    bf16 h = __float2bfloat16(x);
    union { bf16 h; unsigned short u; } c; c.h = h; return c.u;
}

// ---------------- embed: t = np * w_in + b_in + pos_embed ------------------
__global__ __launch_bounds__(256) void embed_kernel(
    const float* __restrict__ npat, const float* __restrict__ w_in,
    const float* __restrict__ b_in, const float* __restrict__ pos,
    float* __restrict__ t, bf16* __restrict__ t_bf)
{
    int n = blockIdx.x;
    int c = threadIdx.x;
    int p = n % 27;
    float v = npat[n] * w_in[c] + b_in[c] + pos[p * DM + c];
    t[(size_t)n * DM + c] = v;
    t_bf[(size_t)n * DM + c] = __float2bfloat16(v);
}

// ---------------- mask: 27-bit token-token mask per query token ------------
// bit m of mask27[b*27+q]: token m is inside q's 3x3x3 window AND known.
__global__ void make_mask_kernel(const int* __restrict__ km,
                                 unsigned int* __restrict__ mask27)
{
    int n = blockIdx.x * blockDim.x + threadIdx.x;
    if (n >= NTOK) return;
    int b = n / 27, q = n % 27;
    int zq = q / 9, yq = (q / 3) % 3, xq = q % 3;
    unsigned int mb = 0u;
    for (int m = 0; m < 27; ++m) {
        int zm = m / 9, ym = (m / 3) % 3, xm = m % 3;
        if (abs(zm - zq) <= 1 && abs(ym - yq) <= 1 && abs(xm - xq) <= 1 &&
            km[b * 27 + m] != 0)
            mb |= (1u << m);
    }
    mask27[n] = mb;
}

// ---------------- weight convert+transpose: W[K][N] f32 -> Wt[N][K] bf16 ---
__global__ __launch_bounds__(256) void convert_weights(
    const float* __restrict__ Wq, const float* __restrict__ Wk,
    const float* __restrict__ Wv, const float* __restrict__ Wo,
    const float* __restrict__ W1, const float* __restrict__ W2,
    bf16* __restrict__ Wt)
{
    __shared__ float tile[32][33];
    int id = blockIdx.z;
    int l = id / 6, wsel = id % 6;
    const float* src; bf16* dst; int K, N;
    if (wsel < 4) {
        const float* tbl[4] = {Wq, Wk, Wv, Wo};
        src = tbl[wsel] + (size_t)l * 65536; K = 256; N = 256;
        dst = Wt + (size_t)l * 786432 + wsel * 65536;
    } else if (wsel == 4) {
        src = W1 + (size_t)l * 262144; K = 256; N = 1024;
        dst = Wt + (size_t)l * 786432 + 262144;
    } else {
        src = W2 + (size_t)l * 262144; K = 1024; N = 256;
        dst = Wt + (size_t)l * 786432 + 524288;
    }
    int n0 = blockIdx.x * 32, k0 = blockIdx.y * 32;
    if (n0 >= N || k0 >= K) return;
    int tx = threadIdx.x, ty = threadIdx.y;   // 32 x 8
#pragma unroll
    for (int i = 0; i < 4; ++i)
        tile[ty + i * 8][tx] = src[(size_t)(k0 + ty + i * 8) * N + n0 + tx];
    __syncthreads();
#pragma unroll
    for (int i = 0; i < 4; ++i)
        dst[(size_t)(n0 + ty + i * 8) * K + k0 + tx] =
            __float2bfloat16(tile[tx][ty + i * 8]);
}

// ---------------- layernorm over d=256, one block per token ----------------
__global__ __launch_bounds__(256) void layernorm_kernel(
    const float* __restrict__ X, const float* __restrict__ g,
    const float* __restrict__ bta, bf16* __restrict__ Y)
{
    int n = blockIdx.x;
    int c = threadIdx.x;
    float x = X[(size_t)n * DM + c];
    float s = x, s2 = x * x;
    for (int off = 32; off; off >>= 1) {
        s  += __shfl_xor(s, off);
        s2 += __shfl_xor(s2, off);
    }
    __shared__ float ps[4], ps2[4];
    int w = c >> 6;
    if ((c & 63) == 0) { ps[w] = s; ps2[w] = s2; }
    __syncthreads();
    s  = ps[0] + ps[1] + ps[2] + ps[3];
    s2 = ps2[0] + ps2[1] + ps2[2] + ps2[3];
    float mu  = s * (1.0f / DM);
    float var = s2 * (1.0f / DM) - mu * mu;
    float r = rsqrtf(var + 1e-5f);
    Y[(size_t)n * DM + c] = __float2bfloat16((x - mu) * r * g[c] + bta[c]);
}

// ---------------- bf16 MFMA GEMM body (128x64 tile, 4 waves) ---------------
// mode 0: normal epilogue (optional f32 + bf16 row-major outputs)
// mode 2: write bf16 output transposed per patch: Cb[(b*256+col)*32 + tok]
__device__ __forceinline__ void gemm_body(
    const bf16* __restrict__ A, const bf16* __restrict__ Bt,
    const float* __restrict__ bias, const float* __restrict__ residual,
    float* __restrict__ Cf, bf16* __restrict__ Cb,
    int K, int Nc, int act, int mode, int row0, int col0,
    bf16* As, bf16* Bs)
{
    int tid = threadIdx.x;
    int wv = tid >> 6, ln = tid & 63;
    int wr = wv >> 1, wc = wv & 1;

    f32x4 acc[4][2];
#pragma unroll
    for (int m = 0; m < 4; ++m)
#pragma unroll
        for (int n = 0; n < 2; ++n) acc[m][n] = (f32x4){0.f, 0.f, 0.f, 0.f};

    int lrow = ln >> 3;          // 0..7 row within 1KB chunk
    int kof  = (ln & 7) * 8;     // bf16 offset within 64-elem row

    for (int k0 = 0; k0 < K; k0 += 64) {
        __syncthreads();
#pragma unroll
        for (int i = 0; i < 4; ++i) {
            int slot = i * 4 + wv;                    // 0..15 (8 rows each)
            gload_lds16(A + (size_t)(row0 + slot * 8 + lrow) * K + k0 + kof,
                        As + slot * 512);
        }
#pragma unroll
        for (int i = 0; i < 2; ++i) {
            int slot = i * 4 + wv;                    // 0..7
            gload_lds16(Bt + (size_t)(col0 + slot * 8 + lrow) * K + k0 + kof,
                        Bs + slot * 512);
        }
        __syncthreads();
        int lr = ln & 15, kg = ln >> 4;
#pragma unroll
        for (int kk = 0; kk < 2; ++kk) {
            int koff = kk * 32 + kg * 8;
            bf16x8 a[4], b[2];
#pragma unroll
            for (int m = 0; m < 4; ++m)
                a[m] = *(const bf16x8*)&As[(wr * 64 + m * 16 + lr) * 64 + koff];
#pragma unroll
            for (int n = 0; n < 2; ++n)
                b[n] = *(const bf16x8*)&Bs[(wc * 32 + n * 16 + lr) * 64 + koff];
#pragma unroll
            for (int m = 0; m < 4; ++m)
#pragma unroll
                for (int n = 0; n < 2; ++n)
                    acc[m][n] = __builtin_amdgcn_mfma_f32_16x16x32_bf16(
                        a[m], b[n], acc[m][n], 0, 0, 0);
        }
    }

    int lr = ln & 15, rg = ln >> 4;
#pragma unroll
    for (int m = 0; m < 4; ++m) {
#pragma unroll
        for (int n = 0; n < 2; ++n) {
            int col = col0 + wc * 32 + n * 16 + lr;
            float bcol = bias[col];
#pragma unroll
            for (int r = 0; r < 4; ++r) {
                int row = row0 + wr * 64 + m * 16 + rg * 4 + r;
                float v = acc[m][n][r] + bcol;
                if (mode == 2) {
                    int bb = row / 27, tok = row - bb * 27;
                    Cb[((size_t)bb * DM + col) * 32 + tok] = __float2bfloat16(v);
                } else {
                    size_t idx = (size_t)row * Nc + col;
                    if (residual) v += residual[idx];
                    if (act) v = 0.5f * v * (1.0f + erff(v * 0.70710678118654752f));
                    if (Cf) Cf[idx] = v;
                    if (Cb) Cb[idx] = __float2bfloat16(v);
                }
            }
        }
    }
}

__global__ __launch_bounds__(256) void gemm_bf16(
    const bf16* __restrict__ A, const bf16* __restrict__ Bt,
    const float* __restrict__ bias, const float* __restrict__ residual,
    float* __restrict__ Cf, bf16* __restrict__ Cb,
    int K, int Nc, int act)
{
    __shared__ __align__(16) bf16 As[128 * 64];
    __shared__ __align__(16) bf16 Bs[64 * 64];
    gemm_body(A, Bt, bias, residual, Cf, Cb, K, Nc, act, 0,
              blockIdx.x * 128, blockIdx.y * 64, As, Bs);
}

// fused Q/K/V projection: grid (54, 12); y>>2 selects {Q,K,V}
// Q,K -> bf16 row-major; V -> bf16 transposed-per-patch Vt[b][d][tok(pad32)]
__global__ __launch_bounds__(256) void qkv_gemm(
    const bf16* __restrict__ tn, const bf16* __restrict__ tb,
    const bf16* __restrict__ wq,              // wq,wk,wv contiguous (65536 apart)
    const float* __restrict__ bq, const float* __restrict__ bk,
    const float* __restrict__ bv,
    bf16* __restrict__ Qb, bf16* __restrict__ Kb, bf16* __restrict__ Vt)
{
    __shared__ __align__(16) bf16 As[128 * 64];
    __shared__ __align__(16) bf16 Bs[64 * 64];
    int ysel = blockIdx.y >> 2, ycol = blockIdx.y & 3;
    const bf16* A = (ysel == 0) ? tn : tb;
    const bf16* W = wq + (size_t)ysel * 65536;
    const float* bias = (ysel == 0) ? bq : (ysel == 1) ? bk : bv;
    bf16* Out = (ysel == 0) ? Qb : (ysel == 1) ? Kb : Vt;
    int mode = (ysel == 2) ? 2 : 0;
    gemm_body(A, W, bias, nullptr, nullptr, Out, DM, DM, 0, mode,
              blockIdx.x * 128, ycol * 64, As, Bs);
}

// ---------------- MFMA attention: one wave per (patch, head) ---------------
// S^T[m][q] = sum_k K[m][k] Q[q][k]  (A = K rows, B = Q rows; K-dim = hd = 32)
// softmax over m (lane-local + shfl 16/32), P -> bf16 via LDS, O = P·V^T.
__global__ __launch_bounds__(256) void attention_mfma(
    const bf16* __restrict__ Qb, const bf16* __restrict__ Kb,
    const bf16* __restrict__ Vt, const unsigned int* __restrict__ mask27,
    bf16* __restrict__ out)
{
    __shared__ __align__(16) bf16 P_lds[4][32 * 40];   // per-wave, pad 40
    int b  = blockIdx.x;
    int wv = threadIdx.x >> 6;
    int head = blockIdx.y * 4 + wv;
    int ln = threadIdx.x & 63;
    int r = ln & 15, g = ln >> 4;        // frag row/col r, k-group g

    const bf16* Kp = Kb + (size_t)b * 27 * DM + head * 32;
    const bf16* Qp = Qb + (size_t)b * 27 * DM + head * 32;

    // fragments: A = K (rows m), B = Q (cols q); k = g*8 + j
    bf16x8 aK[2], bQ[2];
    aK[0] = *(const bf16x8*)(Kp + (size_t)r * DM + g * 8);          // m = r
    aK[1] = *(const bf16x8*)(Kp + (size_t)(16 + r) * DM + g * 8);   // m = 16+r (pad reads OK)
    bQ[0] = *(const bf16x8*)(Qp + (size_t)r * DM + g * 8);          // q = r
    bQ[1] = *(const bf16x8*)(Qp + (size_t)(16 + r) * DM + g * 8);   // q = 16+r

    f32x4 acc[2][2];
#pragma unroll
    for (int at = 0; at < 2; ++at)
#pragma unroll
        for (int bt = 0; bt < 2; ++bt)
            acc[at][bt] = __builtin_amdgcn_mfma_f32_16x16x32_bf16(
                aK[at], bQ[bt], (f32x4){0.f, 0.f, 0.f, 0.f}, 0, 0, 0);

    // masks for this lane's two query columns
    unsigned int Mq[2];
    Mq[0] = mask27[b * 27 + r];
    Mq[1] = (16 + r < 27) ? mask27[b * 27 + 16 + r] : 0u;

    // softmax over m for each query column; C layout: col=lane&15 (q),
    // row m = at*16 + g*4 + reg
#pragma unroll
    for (int bt = 0; bt < 2; ++bt) {
        float e[2][4];
        float mx = -1e30f;
#pragma unroll
        for (int at = 0; at < 2; ++at)
#pragma unroll
            for (int rg = 0; rg < 4; ++rg) {
                int m = at * 16 + g * 4 + rg;
                bool in = (Mq[bt] >> m) & 1;
                float sv = acc[at][bt][rg] * 0.17677669529663687f;
                e[at][rg] = in ? sv : -1e30f;
                mx = fmaxf(mx, e[at][rg]);
            }
        mx = fmaxf(mx, __shfl_xor(mx, 16));
        mx = fmaxf(mx, __shfl_xor(mx, 32));
        float sum = 0.f;
#pragma unroll
        for (int at = 0; at < 2; ++at)
#pragma unroll
            for (int rg = 0; rg < 4; ++rg) {
                int m = at * 16 + g * 4 + rg;
                bool in = (Mq[bt] >> m) & 1;
                float ev = in ? expf(e[at][rg] - mx) : 0.f;
                e[at][rg] = ev;
                sum += ev;
            }
        sum += __shfl_xor(sum, 16);
        sum += __shfl_xor(sum, 32);
        float inv = (sum > 0.f) ? 1.f / sum : 0.f;
        // pack P (bf16) into per-wave LDS: row q = bt*16+r, col m
#pragma unroll
        for (int at = 0; at < 2; ++at) {
            ushort4 u;
            u.x = f2bf_bits(e[at][0] * inv);
            u.y = f2bf_bits(e[at][1] * inv);
            u.z = f2bf_bits(e[at][2] * inv);
            u.w = f2bf_bits(e[at][3] * inv);
            *(ushort4*)&P_lds[wv][(bt * 16 + r) * 40 + at * 16 + g * 4] = u;
        }
    }

    // O[q][d] = sum_m P[q][m] V[m][d];  A = P rows q, B[k=m][col=d] = Vt[d][m]
    bf16x8 pa[2], vb[2];
    pa[0] = *(const bf16x8*)&P_lds[wv][(size_t)r * 40 + g * 8];
    pa[1] = *(const bf16x8*)&P_lds[wv][(size_t)(16 + r) * 40 + g * 8];
    const bf16* Vp = Vt + ((size_t)b * DM + head * 32) * 32;
    vb[0] = *(const bf16x8*)(Vp + (size_t)r * 32 + g * 8);          // d = r
    vb[1] = *(const bf16x8*)(Vp + (size_t)(16 + r) * 32 + g * 8);   // d = 16+r

    f32x4 o[2][2];
#pragma unroll
    for (int qt = 0; qt < 2; ++qt)
#pragma unroll
        for (int dt = 0; dt < 2; ++dt)
            o[qt][dt] = __builtin_amdgcn_mfma_f32_16x16x32_bf16(
                pa[qt], vb[dt], (f32x4){0.f, 0.f, 0.f, 0.f}, 0, 0, 0);

#pragma unroll
    for (int qt = 0; qt < 2; ++qt)
#pragma unroll
        for (int dt = 0; dt < 2; ++dt)
#pragma unroll
            for (int rg = 0; rg < 4; ++rg) {
                int q = qt * 16 + g * 4 + rg;
                if (q < 27)
                    out[(size_t)(b * 27 + q) * DM + head * 32 + dt * 16 + r] =
                        __float2bfloat16(o[qt][dt][rg]);
            }
}

// ---------------- output: out[b] = t[center(b)] . w_out + b_out ------------
__global__ __launch_bounds__(256) void out_proj_kernel(
    const float* __restrict__ t, const float* __restrict__ w_out,
    const float* __restrict__ b_out, float* __restrict__ out)
{
    int bb = blockIdx.x;
    int c = threadIdx.x;
    float v = t[(size_t)(bb * 27 + 13) * DM + c] * w_out[c];
    for (int off = 32; off; off >>= 1) v += __shfl_xor(v, off);
    __shared__ float ps[4];
    if ((c & 63) == 0) ps[c >> 6] = v;
    __syncthreads();
    if (c == 0) out[bb] = ps[0] + ps[1] + ps[2] + ps[3] + b_out[0];
}

// ---------------------------------------------------------------------------
extern "C" void kernel_launch(void* const* d_in, const int* in_sizes, int n_in,
                              void* d_out, int out_size, void* d_ws, size_t ws_size,
                              hipStream_t stream)
{
    const float* npat  = (const float*)d_in[0];
    const int*   kmask = (const int*)  d_in[1];
    const float* w_in  = (const float*)d_in[2];
    const float* b_in  = (const float*)d_in[3];
    const float* pos   = (const float*)d_in[4];
    const float* ln1_g = (const float*)d_in[5];
    const float* ln1_b = (const float*)d_in[6];
    const float* ln2_g = (const float*)d_in[7];
    const float* ln2_b = (const float*)d_in[8];
    const float* Wq    = (const float*)d_in[9];
    const float* bq    = (const float*)d_in[10];
    const float* Wk    = (const float*)d_in[11];
    const float* bk    = (const float*)d_in[12];
    const float* Wv    = (const float*)d_in[13];
    const float* bv    = (const float*)d_in[14];
    const float* Wo    = (const float*)d_in[15];
    const float* bo    = (const float*)d_in[16];
    const float* W1    = (const float*)d_in[17];
    const float* b1    = (const float*)d_in[18];
    const float* W2    = (const float*)d_in[19];
    const float* b2    = (const float*)d_in[20];
    const float* w_out = (const float*)d_in[21];
    const float* b_out = (const float*)d_in[22];
    float* out = (float*)d_out;

    // workspace carve-up
    char* ws = (char*)d_ws;
    size_t f32mat = (size_t)NTOK * DM * 4;   // 7,077,888
    size_t bfmat  = (size_t)NTOK * DM * 2;   // 3,538,944
    float* t = (float*)(ws);
    char* p = ws + f32mat;
    bf16* t_bf   = (bf16*)(p);               p += bfmat;
    bf16* tn_bf  = (bf16*)(p);               p += bfmat;
    bf16* attn_bf= (bf16*)(p);               p += bfmat;
    bf16* Qb     = (bf16*)(p);               p += bfmat;
    bf16* Kb     = (bf16*)(p);               p += bfmat;   // attn over-reads <3KB into Vt: safe
    bf16* Vt     = (bf16*)(p);               p += (size_t)256 * DM * 32 * 2;  // [b][d][tok pad32]
    bf16* H_bf   = (bf16*)(p);               p += (size_t)NTOK * FF * 2;
    bf16* Wt     = (bf16*)(p);               p += (size_t)3 * 786432 * 2;
    unsigned int* mask27 = (unsigned int*)(p);

    convert_weights<<<dim3(32, 32, 18), dim3(32, 8), 0, stream>>>(
        Wq, Wk, Wv, Wo, W1, W2, Wt);
    embed_kernel<<<NTOK, 256, 0, stream>>>(npat, w_in, b_in, pos, t, t_bf);
    make_mask_kernel<<<(NTOK + 255) / 256, 256, 0, stream>>>(kmask, mask27);

    dim3 gDD(NTOK / 128, DM / 64);    // (54, 4)
    dim3 gQKV(NTOK / 128, 12);        // (54, 12)
    dim3 gFF(NTOK / 128, FF / 64);    // (54, 16)

    for (int l = 0; l < 3; ++l) {
        const bf16* wqt = Wt + (size_t)l * 786432;
        const bf16* wot = wqt + 3 * 65536;
        const bf16* w1t = wot + 65536;
        const bf16* w2t = w1t + 262144;

        layernorm_kernel<<<NTOK, 256, 0, stream>>>(t, ln1_g + l * DM, ln1_b + l * DM, tn_bf);
        qkv_gemm<<<gQKV, 256, 0, stream>>>(tn_bf, t_bf, wqt,
                                           bq + l * DM, bk + l * DM, bv + l * DM,
                                           Qb, Kb, Vt);
        attention_mfma<<<dim3(256, 2), 256, 0, stream>>>(Qb, Kb, Vt, mask27, attn_bf);
        gemm_bf16<<<gDD, 256, 0, stream>>>(attn_bf, wot, bo + l * DM, t, t, t_bf, DM, DM, 0);
        layernorm_kernel<<<NTOK, 256, 0, stream>>>(t, ln2_g + l * DM, ln2_b + l * DM, tn_bf);
        gemm_bf16<<<gFF, 256, 0, stream>>>(tn_bf, w1t, b1 + l * FF, nullptr, nullptr, H_bf, DM, FF, 1);
        gemm_bf16<<<gDD, 256, 0, stream>>>(H_bf, w2t, b2 + l * DM, t, t, t_bf, FF, DM, 0);
    }

    out_proj_kernel<<<256, 256, 0, stream>>>(t, w_out, b_out, out);
}